// Round 1
// baseline (936.636 us; speedup 1.0000x reference)
//
#include <hip/hip_runtime.h>
#include <hip/hip_bf16.h>

// USMSharp: img [2,3,1080,1920] f32, kernel [51,51] f32 (separable Gaussian).
// blur = filt(img); res = img-blur; mask = |res|*255>10; soft = filt(mask);
// sharp = clip(img+0.5*res,0,1); out = soft*sharp + (1-soft)*img.
// Strategy: separable conv (row-sum of 2D kernel recovers k1), 5 launches.

#define W 1920
#define H 1080
#define NP 6              // B*C planes
#define PLANE (H * W)     // 2073600
#define TOT (NP * PLANE)  // 12441600
#define R 25              // radius (51 taps)
#define KS 51
#define TV 8              // vertical outputs per thread (1080 % 8 == 0)

__device__ __forceinline__ int reflect_idx(int i, int n) {
    if (i < 0) i = -i;
    if (i >= n) i = 2 * n - 2 - i;
    return i;
}

__global__ void compute_k1(const float* __restrict__ k2d, float* __restrict__ k1) {
    int t = threadIdx.x;
    if (t < KS) {
        float s = 0.f;
        for (int j = 0; j < KS; ++j) s += k2d[t * KS + j];
        k1[t] = s;
    }
}

template <typename T>
__global__ void hblur(const T* __restrict__ in, float* __restrict__ out,
                      const float* __restrict__ k1g) {
    __shared__ float k1[KS];
    __shared__ float row[256 + 2 * R];  // 306
    const int tid = threadIdx.x;
    if (tid < KS) k1[tid] = k1g[tid];
    const int plane = blockIdx.z;
    const int y = blockIdx.y;
    const int x0 = blockIdx.x * 256;
    const T* rin = in + (size_t)plane * PLANE + (size_t)y * W;
    for (int t = tid; t < 256 + 2 * R; t += 256) {
        int xi = reflect_idx(x0 - R + t, W);
        row[t] = (float)rin[xi];
    }
    __syncthreads();
    const int x = x0 + tid;
    if (x < W) {
        float s = 0.f;
#pragma unroll
        for (int i = 0; i < KS; ++i) s += k1[i] * row[tid + i];
        out[(size_t)plane * PLANE + (size_t)y * W + x] = s;
    }
}

// vertical blur of A; then residual/mask/sharp from img. mask->u8, sharp->out.
__global__ void vblur_mask_sharp(const float* __restrict__ A, const float* __restrict__ img,
                                 const float* __restrict__ k1g,
                                 unsigned char* __restrict__ mask, float* __restrict__ sharp) {
    __shared__ float k1[KS];
    const int tid = threadIdx.x;
    if (tid < KS) k1[tid] = k1g[tid];
    __syncthreads();
    const int plane = blockIdx.z;
    const int y0 = blockIdx.y * TV;
    const int x = blockIdx.x * 256 + tid;
    if (x >= W) return;
    const float* Ap = A + (size_t)plane * PLANE;
    float acc[TV];
#pragma unroll
    for (int o = 0; o < TV; ++o) acc[o] = 0.f;
    for (int dy = -R; dy < TV + R; ++dy) {
        int yy = reflect_idx(y0 + dy, H);
        float v = Ap[(size_t)yy * W + x];
        int olo = dy - R > 0 ? dy - R : 0;
        int ohi = dy + R < TV - 1 ? dy + R : TV - 1;
        for (int o = olo; o <= ohi; ++o) acc[o] += k1[dy - o + R] * v;
    }
#pragma unroll
    for (int o = 0; o < TV; ++o) {
        size_t idx = (size_t)plane * PLANE + (size_t)(y0 + o) * W + x;
        float iv = img[idx];
        float r = iv - acc[o];
        mask[idx] = (fabsf(r) * 255.f > 10.f) ? (unsigned char)1 : (unsigned char)0;
        float sh = iv + 0.5f * r;
        sh = fminf(fmaxf(sh, 0.f), 1.f);
        sharp[idx] = sh;
    }
}

// vertical blur of A (h-blurred mask) -> soft_mask; blend in-place on out (holds sharp).
__global__ void vblur_blend(const float* __restrict__ A, const float* __restrict__ img,
                            const float* __restrict__ k1g, float* __restrict__ out) {
    __shared__ float k1[KS];
    const int tid = threadIdx.x;
    if (tid < KS) k1[tid] = k1g[tid];
    __syncthreads();
    const int plane = blockIdx.z;
    const int y0 = blockIdx.y * TV;
    const int x = blockIdx.x * 256 + tid;
    if (x >= W) return;
    const float* Ap = A + (size_t)plane * PLANE;
    float acc[TV];
#pragma unroll
    for (int o = 0; o < TV; ++o) acc[o] = 0.f;
    for (int dy = -R; dy < TV + R; ++dy) {
        int yy = reflect_idx(y0 + dy, H);
        float v = Ap[(size_t)yy * W + x];
        int olo = dy - R > 0 ? dy - R : 0;
        int ohi = dy + R < TV - 1 ? dy + R : TV - 1;
        for (int o = olo; o <= ohi; ++o) acc[o] += k1[dy - o + R] * v;
    }
#pragma unroll
    for (int o = 0; o < TV; ++o) {
        size_t idx = (size_t)plane * PLANE + (size_t)(y0 + o) * W + x;
        float iv = img[idx];
        float sh = out[idx];
        float sm = acc[o];
        out[idx] = iv + sm * (sh - iv);
    }
}

extern "C" void kernel_launch(void* const* d_in, const int* in_sizes, int n_in,
                              void* d_out, int out_size, void* d_ws, size_t ws_size,
                              hipStream_t stream) {
    const float* img = (const float*)d_in[0];
    const float* k2d = (const float*)d_in[1];
    float* out = (float*)d_out;

    // ws layout: A (TOT f32) | k1 (64 f32) | mask (TOT u8)  => ~62.2 MB
    float* A = (float*)d_ws;
    float* k1 = A + TOT;
    unsigned char* maskB = (unsigned char*)(k1 + 64);

    dim3 gridH((W + 255) / 256, H, NP);
    dim3 gridV((W + 255) / 256, H / TV, NP);

    hipLaunchKernelGGL(compute_k1, dim3(1), dim3(64), 0, stream, k2d, k1);
    hipLaunchKernelGGL(hblur<float>, gridH, dim3(256), 0, stream, img, A, k1);
    hipLaunchKernelGGL(vblur_mask_sharp, gridV, dim3(256), 0, stream, A, img, k1, maskB, out);
    hipLaunchKernelGGL(hblur<unsigned char>, gridH, dim3(256), 0, stream, maskB, A, k1);
    hipLaunchKernelGGL(vblur_blend, gridV, dim3(256), 0, stream, A, img, k1, out);
}

// Round 2
// 316.686 us; speedup vs baseline: 2.9576x; 2.9576x over previous
//
#include <hip/hip_runtime.h>
#include <hip/hip_bf16.h>

// USMSharp: img [2,3,1080,1920] f32, kernel [51,51] f32 (separable Gaussian).
// blur = filt(img); res = img-blur; mask = |res|*255>10; soft = filt(mask);
// sharp = clip(img+0.5*res,0,1); out = soft*sharp + (1-soft)*img.
// R2: fully-unrolled static-bound conv loops, float4-wide vblur,
//     k1 via uniform (scalarized) global loads, 4-wide hblur from LDS.

#define W 1920
#define H 1080
#define NP 6
#define PLANE (H * W)
#define TOT (NP * PLANE)
#define R 25
#define KS 51
#define TV 8   // vertical outputs per thread (rows); 1080 % 8 == 0
#define HCOLS 1024  // columns per hblur block

__device__ __forceinline__ int reflect_idx(int i, int n) {
    if (i < 0) i = -i;
    if (i >= n) i = 2 * n - 2 - i;
    return i;
}

__global__ void compute_k1(const float* __restrict__ k2d, float* __restrict__ k1) {
    int t = threadIdx.x;
    if (t < KS) {
        float s = 0.f;
        for (int j = 0; j < KS; ++j) s += k2d[t * KS + j];
        k1[t] = s;
    }
}

// Horizontal blur: 4 outputs/thread, LDS row staging, k1 from SGPR-scalarized loads.
template <typename T>
__global__ void hblur(const T* __restrict__ in, float* __restrict__ out,
                      const float* __restrict__ k1g) {
    __shared__ __align__(16) float row[HCOLS + 2 * R];  // 1074 floats
    const int tid = threadIdx.x;
    const int plane = blockIdx.z;
    const int y = blockIdx.y;
    const int x0 = blockIdx.x * HCOLS;
    const T* rin = in + (size_t)plane * PLANE + (size_t)y * W;
    for (int t = tid; t < HCOLS + 2 * R; t += 256) {
        int xi = reflect_idx(x0 - R + t, W);
        row[t] = (float)rin[xi];
    }
    __syncthreads();
    const int x4 = x0 + 4 * tid;
    if (x4 >= W) return;
    float acc0 = 0.f, acc1 = 0.f, acc2 = 0.f, acc3 = 0.f;
#pragma unroll
    for (int i = 0; i < 14; ++i) {
        float4 v = *(const float4*)&row[4 * tid + 4 * i];
#pragma unroll
        for (int j = 0; j < 4; ++j) {
            const int p = 4 * i + j;
            const float vv = (j == 0) ? v.x : (j == 1) ? v.y : (j == 2) ? v.z : v.w;
            if (p >= 0 && p <= 50) acc0 += k1g[p] * vv;
            if (p - 1 >= 0 && p - 1 <= 50) acc1 += k1g[p - 1] * vv;
            if (p - 2 >= 0 && p - 2 <= 50) acc2 += k1g[p - 2] * vv;
            if (p - 3 >= 0 && p - 3 <= 50) acc3 += k1g[p - 3] * vv;
        }
    }
    float4 o4 = make_float4(acc0, acc1, acc2, acc3);
    *(float4*)&out[(size_t)plane * PLANE + (size_t)y * W + x4] = o4;
}

// Vertical 51-tap conv of Ap at (x4, y0..y0+TV-1), float4-wide. Fully unrolled.
__device__ __forceinline__ void vconv(const float* __restrict__ Ap, int x4, int y0,
                                      const float* __restrict__ k1g, float4 acc[TV]) {
#pragma unroll
    for (int o = 0; o < TV; ++o) acc[o] = make_float4(0.f, 0.f, 0.f, 0.f);
    if (y0 >= R && y0 + TV - 1 + R < H) {
        const float* p = Ap + (size_t)(y0 - R) * W + x4;
#pragma unroll
        for (int dy = -R; dy < TV + R; ++dy) {
            float4 v = *(const float4*)p;
            p += W;
            const int olo = (dy - R > 0) ? dy - R : 0;
            const int ohi = (dy + R < TV - 1) ? dy + R : TV - 1;
#pragma unroll
            for (int o = olo; o <= ohi; ++o) {
                const float k = k1g[dy - o + R];
                acc[o].x += k * v.x; acc[o].y += k * v.y;
                acc[o].z += k * v.z; acc[o].w += k * v.w;
            }
        }
    } else {
#pragma unroll
        for (int dy = -R; dy < TV + R; ++dy) {
            int yy = reflect_idx(y0 + dy, H);
            float4 v = *(const float4*)(Ap + (size_t)yy * W + x4);
            const int olo = (dy - R > 0) ? dy - R : 0;
            const int ohi = (dy + R < TV - 1) ? dy + R : TV - 1;
#pragma unroll
            for (int o = olo; o <= ohi; ++o) {
                const float k = k1g[dy - o + R];
                acc[o].x += k * v.x; acc[o].y += k * v.y;
                acc[o].z += k * v.z; acc[o].w += k * v.w;
            }
        }
    }
}

__global__ void vblur_mask_sharp(const float* __restrict__ A, const float* __restrict__ img,
                                 const float* __restrict__ k1g,
                                 unsigned char* __restrict__ mask, float* __restrict__ sharp) {
    const int plane = blockIdx.z;
    const int y0 = blockIdx.y * TV;
    const int x4 = (blockIdx.x * 256 + threadIdx.x) * 4;
    if (x4 >= W) return;
    float4 acc[TV];
    vconv(A + (size_t)plane * PLANE, x4, y0, k1g, acc);
#pragma unroll
    for (int o = 0; o < TV; ++o) {
        size_t idx = (size_t)plane * PLANE + (size_t)(y0 + o) * W + x4;
        float4 iv = *(const float4*)&img[idx];
        float rx = iv.x - acc[o].x, ry = iv.y - acc[o].y;
        float rz = iv.z - acc[o].z, rw = iv.w - acc[o].w;
        uchar4 m;
        m.x = (fabsf(rx) * 255.f > 10.f) ? 1 : 0;
        m.y = (fabsf(ry) * 255.f > 10.f) ? 1 : 0;
        m.z = (fabsf(rz) * 255.f > 10.f) ? 1 : 0;
        m.w = (fabsf(rw) * 255.f > 10.f) ? 1 : 0;
        *(uchar4*)&mask[idx] = m;
        float4 sh;
        sh.x = fminf(fmaxf(iv.x + 0.5f * rx, 0.f), 1.f);
        sh.y = fminf(fmaxf(iv.y + 0.5f * ry, 0.f), 1.f);
        sh.z = fminf(fmaxf(iv.z + 0.5f * rz, 0.f), 1.f);
        sh.w = fminf(fmaxf(iv.w + 0.5f * rw, 0.f), 1.f);
        *(float4*)&sharp[idx] = sh;
    }
}

__global__ void vblur_blend(const float* __restrict__ A, const float* __restrict__ img,
                            const float* __restrict__ k1g, float* __restrict__ out) {
    const int plane = blockIdx.z;
    const int y0 = blockIdx.y * TV;
    const int x4 = (blockIdx.x * 256 + threadIdx.x) * 4;
    if (x4 >= W) return;
    float4 acc[TV];
    vconv(A + (size_t)plane * PLANE, x4, y0, k1g, acc);
#pragma unroll
    for (int o = 0; o < TV; ++o) {
        size_t idx = (size_t)plane * PLANE + (size_t)(y0 + o) * W + x4;
        float4 iv = *(const float4*)&img[idx];
        float4 sh = *(const float4*)&out[idx];
        float4 r;
        r.x = iv.x + acc[o].x * (sh.x - iv.x);
        r.y = iv.y + acc[o].y * (sh.y - iv.y);
        r.z = iv.z + acc[o].z * (sh.z - iv.z);
        r.w = iv.w + acc[o].w * (sh.w - iv.w);
        *(float4*)&out[idx] = r;
    }
}

extern "C" void kernel_launch(void* const* d_in, const int* in_sizes, int n_in,
                              void* d_out, int out_size, void* d_ws, size_t ws_size,
                              hipStream_t stream) {
    const float* img = (const float*)d_in[0];
    const float* k2d = (const float*)d_in[1];
    float* out = (float*)d_out;

    // ws layout: A (TOT f32) | k1 (64 f32) | mask (TOT u8)
    float* A = (float*)d_ws;
    float* k1 = A + TOT;
    unsigned char* maskB = (unsigned char*)(k1 + 64);

    dim3 gridH((W + HCOLS - 1) / HCOLS, H, NP);     // (2, 1080, 6)
    dim3 gridV((W / 4 + 255) / 256, H / TV, NP);    // (2, 135, 6)

    hipLaunchKernelGGL(compute_k1, dim3(1), dim3(64), 0, stream, k2d, k1);
    hipLaunchKernelGGL(hblur<float>, gridH, dim3(256), 0, stream, img, A, k1);
    hipLaunchKernelGGL(vblur_mask_sharp, gridV, dim3(256), 0, stream, A, img, k1, maskB, out);
    hipLaunchKernelGGL(hblur<unsigned char>, gridH, dim3(256), 0, stream, maskB, A, k1);
    hipLaunchKernelGGL(vblur_blend, gridV, dim3(256), 0, stream, A, img, k1, out);
}

// Round 3
// 301.686 us; speedup vs baseline: 3.1047x; 1.0497x over previous
//
#include <hip/hip_runtime.h>
#include <hip/hip_bf16.h>

// USMSharp R3: separable conv pipeline with bf16 intermediates.
// K1 hblur(img f32) -> A bf16 ; K2 vblur(A)+mask(u8)+d=sharp-img(bf16)
// K3 hblur(mask u8) -> Bh bf16 (aliases A) ; K4 vblur(Bh)+out=img+soft*d.
// ws = A/Bh (u16 TOT) | k1 | mask (u8 TOT) | d (u16 TOT) = 62,208,256 B.

#define W 1920
#define H 1080
#define NP 6
#define PLANE (H * W)
#define TOT (NP * PLANE)
#define R 25
#define KS 51
#define TV 15        // 1080 = 15*72
#define HCOLS 1024

__device__ __forceinline__ int reflect_idx(int i, int n) {
    if (i < 0) i = -i;
    if (i >= n) i = 2 * n - 2 - i;
    return i;
}
__device__ __forceinline__ float bf2f(unsigned short u) {
    return __uint_as_float(((unsigned int)u) << 16);
}
__device__ __forceinline__ unsigned short f2bf(float f) {  // round-to-nearest-even
    unsigned int x = __float_as_uint(f);
    return (unsigned short)((x + 0x7FFFu + ((x >> 16) & 1u)) >> 16);
}

__global__ void compute_k1(const float* __restrict__ k2d, float* __restrict__ k1) {
    int t = threadIdx.x;
    if (t < KS) {
        float s = 0.f;
        for (int j = 0; j < KS; ++j) s += k2d[t * KS + j];
        k1[t] = s;
    }
}

// Horizontal blur: T in (f32 or u8), bf16 out. 4 outputs/thread via LDS row.
template <typename T>
__global__ void hblur(const T* __restrict__ in, unsigned short* __restrict__ out,
                      const float* __restrict__ k1g) {
    __shared__ __align__(16) float row[HCOLS + 2 * R];  // 1074
    const int tid = threadIdx.x;
    const int plane = blockIdx.z;
    const int y = blockIdx.y;
    const int x0 = blockIdx.x * HCOLS;
    const T* rin = in + (size_t)plane * PLANE + (size_t)y * W;
    for (int t = tid; t < HCOLS + 2 * R; t += 256) {
        int xi = reflect_idx(x0 - R + t, W);
        row[t] = (float)rin[xi];
    }
    __syncthreads();
    const int x4 = x0 + 4 * tid;
    if (x4 >= W) return;
    float acc0 = 0.f, acc1 = 0.f, acc2 = 0.f, acc3 = 0.f;
#pragma unroll
    for (int i = 0; i < 14; ++i) {
        float4 v = *(const float4*)&row[4 * tid + 4 * i];
#pragma unroll
        for (int j = 0; j < 4; ++j) {
            const int p = 4 * i + j;
            const float vv = (j == 0) ? v.x : (j == 1) ? v.y : (j == 2) ? v.z : v.w;
            if (p >= 0 && p <= 50) acc0 += k1g[p] * vv;
            if (p - 1 >= 0 && p - 1 <= 50) acc1 += k1g[p - 1] * vv;
            if (p - 2 >= 0 && p - 2 <= 50) acc2 += k1g[p - 2] * vv;
            if (p - 3 >= 0 && p - 3 <= 50) acc3 += k1g[p - 3] * vv;
        }
    }
    ushort4 o;
    o.x = f2bf(acc0); o.y = f2bf(acc1); o.z = f2bf(acc2); o.w = f2bf(acc3);
    *(ushort4*)&out[(size_t)plane * PLANE + (size_t)y * W + x4] = o;
}

// Vertical 51-tap conv of bf16 plane at (x4, y0..y0+TV-1). Fully unrolled.
__device__ __forceinline__ void vconv_bf16(const unsigned short* __restrict__ Ap, int x4, int y0,
                                           const float* __restrict__ k1g, float4 acc[TV]) {
#pragma unroll
    for (int o = 0; o < TV; ++o) acc[o] = make_float4(0.f, 0.f, 0.f, 0.f);
    if (y0 >= R && y0 + TV - 1 + R < H) {
        const unsigned short* p = Ap + (size_t)(y0 - R) * W + x4;
#pragma unroll
        for (int dy = -R; dy < TV + R; ++dy) {
            ushort4 u = *(const ushort4*)p;
            p += W;
            float4 v = make_float4(bf2f(u.x), bf2f(u.y), bf2f(u.z), bf2f(u.w));
            const int olo = (dy - R > 0) ? dy - R : 0;
            const int ohi = (dy + R < TV - 1) ? dy + R : TV - 1;
#pragma unroll
            for (int o = olo; o <= ohi; ++o) {
                const float k = k1g[dy - o + R];
                acc[o].x += k * v.x; acc[o].y += k * v.y;
                acc[o].z += k * v.z; acc[o].w += k * v.w;
            }
        }
    } else {
#pragma unroll
        for (int dy = -R; dy < TV + R; ++dy) {
            int yy = reflect_idx(y0 + dy, H);
            ushort4 u = *(const ushort4*)(Ap + (size_t)yy * W + x4);
            float4 v = make_float4(bf2f(u.x), bf2f(u.y), bf2f(u.z), bf2f(u.w));
            const int olo = (dy - R > 0) ? dy - R : 0;
            const int ohi = (dy + R < TV - 1) ? dy + R : TV - 1;
#pragma unroll
            for (int o = olo; o <= ohi; ++o) {
                const float k = k1g[dy - o + R];
                acc[o].x += k * v.x; acc[o].y += k * v.y;
                acc[o].z += k * v.z; acc[o].w += k * v.w;
            }
        }
    }
}

// vblur(A) -> blur; mask u8; d = clip(img+0.5*(img-blur),0,1) - img as bf16.
__global__ void vblur_mask_d(const unsigned short* __restrict__ A, const float* __restrict__ img,
                             const float* __restrict__ k1g,
                             unsigned char* __restrict__ mask, unsigned short* __restrict__ d) {
    const int plane = blockIdx.z;
    const int y0 = blockIdx.y * TV;
    const int x4 = (blockIdx.x * 256 + threadIdx.x) * 4;
    if (x4 >= W) return;
    float4 acc[TV];
    vconv_bf16(A + (size_t)plane * PLANE, x4, y0, k1g, acc);
#pragma unroll
    for (int o = 0; o < TV; ++o) {
        size_t idx = (size_t)plane * PLANE + (size_t)(y0 + o) * W + x4;
        float4 iv = *(const float4*)&img[idx];
        float rx = iv.x - acc[o].x, ry = iv.y - acc[o].y;
        float rz = iv.z - acc[o].z, rw = iv.w - acc[o].w;
        uchar4 m;
        m.x = (fabsf(rx) * 255.f > 10.f) ? 1 : 0;
        m.y = (fabsf(ry) * 255.f > 10.f) ? 1 : 0;
        m.z = (fabsf(rz) * 255.f > 10.f) ? 1 : 0;
        m.w = (fabsf(rw) * 255.f > 10.f) ? 1 : 0;
        *(uchar4*)&mask[idx] = m;
        ushort4 dd;
        dd.x = f2bf(fminf(fmaxf(iv.x + 0.5f * rx, 0.f), 1.f) - iv.x);
        dd.y = f2bf(fminf(fmaxf(iv.y + 0.5f * ry, 0.f), 1.f) - iv.y);
        dd.z = f2bf(fminf(fmaxf(iv.z + 0.5f * rz, 0.f), 1.f) - iv.z);
        dd.w = f2bf(fminf(fmaxf(iv.w + 0.5f * rw, 0.f), 1.f) - iv.w);
        *(ushort4*)&d[idx] = dd;
    }
}

// vblur(Bh) -> soft; out = img + soft * d.
__global__ void vblur_blend(const unsigned short* __restrict__ Bh, const float* __restrict__ img,
                            const unsigned short* __restrict__ d, const float* __restrict__ k1g,
                            float* __restrict__ out) {
    const int plane = blockIdx.z;
    const int y0 = blockIdx.y * TV;
    const int x4 = (blockIdx.x * 256 + threadIdx.x) * 4;
    if (x4 >= W) return;
    float4 acc[TV];
    vconv_bf16(Bh + (size_t)plane * PLANE, x4, y0, k1g, acc);
#pragma unroll
    for (int o = 0; o < TV; ++o) {
        size_t idx = (size_t)plane * PLANE + (size_t)(y0 + o) * W + x4;
        float4 iv = *(const float4*)&img[idx];
        ushort4 du = *(const ushort4*)&d[idx];
        float4 r;
        r.x = iv.x + acc[o].x * bf2f(du.x);
        r.y = iv.y + acc[o].y * bf2f(du.y);
        r.z = iv.z + acc[o].z * bf2f(du.z);
        r.w = iv.w + acc[o].w * bf2f(du.w);
        *(float4*)&out[idx] = r;
    }
}

extern "C" void kernel_launch(void* const* d_in, const int* in_sizes, int n_in,
                              void* d_out, int out_size, void* d_ws, size_t ws_size,
                              hipStream_t stream) {
    const float* img = (const float*)d_in[0];
    const float* k2d = (const float*)d_in[1];
    float* out = (float*)d_out;

    // ws: A/Bh (u16 TOT) | k1 (64 f32) | mask (u8 TOT) | d (u16 TOT) = 62,208,256 B
    unsigned short* AB = (unsigned short*)d_ws;
    float* k1 = (float*)(AB + TOT);
    unsigned char* maskB = (unsigned char*)(k1 + 64);
    unsigned short* dBuf = (unsigned short*)(maskB + TOT);

    dim3 gridH((W + HCOLS - 1) / HCOLS, H, NP);   // (2, 1080, 6)
    dim3 gridV((W / 4 + 255) / 256, H / TV, NP);  // (2, 72, 6)

    hipLaunchKernelGGL(compute_k1, dim3(1), dim3(64), 0, stream, k2d, k1);
    hipLaunchKernelGGL(hblur<float>, gridH, dim3(256), 0, stream, img, AB, k1);
    hipLaunchKernelGGL(vblur_mask_d, gridV, dim3(256), 0, stream, AB, img, k1, maskB, dBuf);
    hipLaunchKernelGGL(hblur<unsigned char>, gridH, dim3(256), 0, stream, maskB, AB, k1);
    hipLaunchKernelGGL(vblur_blend, gridV, dim3(256), 0, stream, AB, img, dBuf, k1, out);
}